// Round 1
// baseline (226.461 us; speedup 1.0000x reference)
//
#include <hip/hip_runtime.h>

// Bidirectional GRU (H=32, input=1, B=2048, T=512) + MLP head, fully fused.
//
// Key insight: reference takes out[:, -1, :] = concat(h_fwd after T steps,
// h_bwd after ONE step from h0=0 consuming x[T-1]).  So only the forward
// direction needs the sequential scan; W_hh_b is entirely unused.
//
// Decomposition: 32 lanes per batch row, 2 rows per wave64, no cross-wave
// communication -> zero __syncthreads.  Lane i holds W_hh rows {i,32+i,64+i}
// in VGPRs; h is broadcast per step through LDS (ds_write_b32 + 8x
// ds_read_b128, conflict-free broadcast reads).

typedef float vf2 __attribute__((ext_vector_type(2)));

#define TT 512
#define HH 32

__device__ __forceinline__ float sigm(float a) {
  return 1.0f / (1.0f + __expf(-a));
}
// tanh(a) = 1 - 2/(exp(2a)+1); correct limits at +/-inf in fp32.
__device__ __forceinline__ float tanh_(float a) {
  return 1.0f - 2.0f / (1.0f + __expf(2.0f * a));
}

__global__ __launch_bounds__(256)
void gru_bidir_head(const float* __restrict__ X,
                    const float* __restrict__ Wih_f, const float* __restrict__ Whh_f,
                    const float* __restrict__ bih_f, const float* __restrict__ bhh_f,
                    const float* __restrict__ Wih_b,
                    const float* __restrict__ bih_b, const float* __restrict__ bhh_b,
                    const float* __restrict__ W1, const float* __restrict__ b1,
                    const float* __restrict__ W2, const float* __restrict__ b2,
                    float* __restrict__ out)
{
  __shared__ float hbuf[8][64];            // [row-in-block][h_f(0..31) | h_b(32..63)]
  const int g  = threadIdx.x & 31;         // lane within row-group
  const int wr = threadIdx.x >> 5;         // row within block (0..7)
  const int b  = (blockIdx.x << 3) + wr;   // global batch row

  // --- per-lane recurrent weights: W_hh rows g (r), 32+g (z), 64+g (n) ---
  vf2 w_r[16], w_z[16], w_n[16];
  const vf2* Whh2 = (const vf2*)Whh_f;
  #pragma unroll
  for (int q = 0; q < 16; ++q) {
    w_r[q] = Whh2[(g)        * 16 + q];
    w_z[q] = Whh2[(HH + g)   * 16 + q];
    w_n[q] = Whh2[(2*HH + g) * 16 + q];
  }
  const float wir = Wih_f[g], wiz = Wih_f[HH + g], win = Wih_f[2*HH + g];
  const float brs = bih_f[g]        + bhh_f[g];        // fold b_ih + b_hh for r
  const float bzs = bih_f[HH + g]   + bhh_f[HH + g];   // fold for z
  const float bin = bih_f[2*HH + g];                   // n keeps them separate:
  const float bhn = bhh_f[2*HH + g];                   // n = tanh(xn + r*(dot + bhn))

  const float* Xrow = X + (size_t)b * TT;
  const float4* hv4 = (const float4*)(&hbuf[wr][0]);

  float h = 0.0f;
  hbuf[wr][g] = 0.0f;
  __builtin_amdgcn_wave_barrier();

  float x_next = Xrow[0];
  #pragma unroll 1
  for (int t = 0; t < TT; ++t) {
    const float x = x_next;
    x_next = Xrow[t < TT - 1 ? t + 1 : t];     // prefetch next step's scalar input

    vf2 ar = { __builtin_fmaf(x, wir, brs), 0.0f };
    vf2 az = { __builtin_fmaf(x, wiz, bzs), 0.0f };
    vf2 an = { bhn, 0.0f };
    const float xn = __builtin_fmaf(x, win, bin);

    #pragma unroll
    for (int q = 0; q < 8; ++q) {
      float4 h4 = hv4[q];                      // broadcast ds_read_b128
      vf2 hlo = { h4.x, h4.y };
      vf2 hhi = { h4.z, h4.w };
      ar = __builtin_elementwise_fma(hlo, w_r[2*q],     ar);
      az = __builtin_elementwise_fma(hlo, w_z[2*q],     az);
      an = __builtin_elementwise_fma(hlo, w_n[2*q],     an);
      ar = __builtin_elementwise_fma(hhi, w_r[2*q + 1], ar);
      az = __builtin_elementwise_fma(hhi, w_z[2*q + 1], az);
      an = __builtin_elementwise_fma(hhi, w_n[2*q + 1], an);
    }
    const float r = sigm(ar.x + ar.y);
    const float z = sigm(az.x + az.y);
    const float n = tanh_(__builtin_fmaf(r, an.x + an.y, xn));
    h = __builtin_fmaf(z, h - n, n);           // (1-z)*n + z*h

    hbuf[wr][g] = h;
    __builtin_amdgcn_wave_barrier();           // wave-synchronous LDS: pin ordering
  }

  // --- backward direction: exactly ONE GRU step from h0=0 on x[T-1] ---
  const float xl  = Xrow[TT - 1];
  const float rb  = sigm(__builtin_fmaf(xl, Wih_b[g],        bih_b[g]        + bhh_b[g]));
  const float zb  = sigm(__builtin_fmaf(xl, Wih_b[HH + g],   bih_b[HH + g]   + bhh_b[HH + g]));
  const float xnb =       __builtin_fmaf(xl, Wih_b[2*HH + g], bih_b[2*HH + g]);
  const float nb  = tanh_(__builtin_fmaf(rb, bhh_b[2*HH + g], xnb));
  const float hb  = nb - zb * nb;              // (1-zb)*nb + zb*0

  // --- MLP head: sigmoid(W2 @ relu(W1 @ [h_f, h_b] + b1) + b2) ---
  hbuf[wr][g]      = h;                        // h_f
  hbuf[wr][32 + g] = hb;                       // h_b
  __builtin_amdgcn_wave_barrier();

  const int j = g & 15;                        // lanes 16..31 duplicate, harmless
  const float4* W1r = (const float4*)(W1 + j * 64);
  const float4* hc4 = (const float4*)(&hbuf[wr][0]);
  float acc = b1[j];
  #pragma unroll
  for (int q = 0; q < 16; ++q) {
    float4 w  = W1r[q];
    float4 hq = hc4[q];
    acc += w.x * hq.x + w.y * hq.y + w.z * hq.z + w.w * hq.w;
  }
  float h1 = fmaxf(acc, 0.0f) * W2[j];
  h1 += __shfl_down(h1, 8, 16);
  h1 += __shfl_down(h1, 4, 16);
  h1 += __shfl_down(h1, 2, 16);
  h1 += __shfl_down(h1, 1, 16);
  if (g == 0) out[b] = sigm(h1 + b2[0]);
}

extern "C" void kernel_launch(void* const* d_in, const int* in_sizes, int n_in,
                              void* d_out, int out_size, void* d_ws, size_t ws_size,
                              hipStream_t stream) {
  const float* X     = (const float*)d_in[0];
  const float* Wih_f = (const float*)d_in[1];
  const float* Whh_f = (const float*)d_in[2];
  const float* bih_f = (const float*)d_in[3];
  const float* bhh_f = (const float*)d_in[4];
  const float* Wih_b = (const float*)d_in[5];
  // d_in[6] = W_hh_b: unused — backward direction runs exactly one step from h0=0.
  const float* bih_b = (const float*)d_in[7];
  const float* bhh_b = (const float*)d_in[8];
  const float* W1    = (const float*)d_in[9];
  const float* b1    = (const float*)d_in[10];
  const float* W2    = (const float*)d_in[11];
  const float* b2    = (const float*)d_in[12];
  float* out = (float*)d_out;

  // 2048 rows / 8 rows per block = 256 blocks of 256 threads (1 per CU).
  gru_bidir_head<<<256, 256, 0, stream>>>(X, Wih_f, Whh_f, bih_f, bhh_f,
                                          Wih_b, bih_b, bhh_b, W1, b1, W2, b2, out);
}

// Round 2
// 226.158 us; speedup vs baseline: 1.0013x; 1.0013x over previous
//
#include <hip/hip_runtime.h>

// Bidirectional GRU (H=32, input=1, B=2048, T=512) + MLP head, fully fused.
//
// Key insight: reference takes out[:, -1, :] = concat(h_fwd after T steps,
// h_bwd after ONE step from h0=0 consuming x[T-1]).  So only the forward
// direction needs the sequential scan; W_hh_b is entirely unused.
//
// Decomposition: 32 lanes per batch row, 2 rows per wave64, no cross-wave
// communication -> zero __syncthreads.  Lane i holds W_hh rows {i,32+i,64+i}
// in VGPRs; h is broadcast per step through LDS (ds_write_b32 + 8x
// ds_read_b128, conflict-free broadcast reads).
//
// R2: __launch_bounds__(256, 1).  R1's (256) default let the allocator cap at
// 80 VGPRs, spilling the 96 resident weight registers to scratch ->
// FETCH_SIZE 2.15 GB of spill reloads.  min-waves=1 allows up to 512
// VGPRs/wave so w_r/w_z/w_n stay in registers; we only ever run 1 wave/SIMD
// anyway (1024 waves total on 1024 SIMDs).

typedef float vf2 __attribute__((ext_vector_type(2)));

#define TT 512
#define HH 32

__device__ __forceinline__ float sigm(float a) {
  return 1.0f / (1.0f + __expf(-a));
}
// tanh(a) = 1 - 2/(exp(2a)+1); correct limits at +/-inf in fp32.
__device__ __forceinline__ float tanh_(float a) {
  return 1.0f - 2.0f / (1.0f + __expf(2.0f * a));
}

__global__ __launch_bounds__(256, 1)
void gru_bidir_head(const float* __restrict__ X,
                    const float* __restrict__ Wih_f, const float* __restrict__ Whh_f,
                    const float* __restrict__ bih_f, const float* __restrict__ bhh_f,
                    const float* __restrict__ Wih_b,
                    const float* __restrict__ bih_b, const float* __restrict__ bhh_b,
                    const float* __restrict__ W1, const float* __restrict__ b1,
                    const float* __restrict__ W2, const float* __restrict__ b2,
                    float* __restrict__ out)
{
  __shared__ float hbuf[8][64];            // [row-in-block][h_f(0..31) | h_b(32..63)]
  const int g  = threadIdx.x & 31;         // lane within row-group
  const int wr = threadIdx.x >> 5;         // row within block (0..7)
  const int b  = (blockIdx.x << 3) + wr;   // global batch row

  // --- per-lane recurrent weights: W_hh rows g (r), 32+g (z), 64+g (n) ---
  vf2 w_r[16], w_z[16], w_n[16];
  const vf2* Whh2 = (const vf2*)Whh_f;
  #pragma unroll
  for (int q = 0; q < 16; ++q) {
    w_r[q] = Whh2[(g)        * 16 + q];
    w_z[q] = Whh2[(HH + g)   * 16 + q];
    w_n[q] = Whh2[(2*HH + g) * 16 + q];
  }
  const float wir = Wih_f[g], wiz = Wih_f[HH + g], win = Wih_f[2*HH + g];
  const float brs = bih_f[g]        + bhh_f[g];        // fold b_ih + b_hh for r
  const float bzs = bih_f[HH + g]   + bhh_f[HH + g];   // fold for z
  const float bin = bih_f[2*HH + g];                   // n keeps them separate:
  const float bhn = bhh_f[2*HH + g];                   // n = tanh(xn + r*(dot + bhn))

  const float* Xrow = X + (size_t)b * TT;
  const float4* hv4 = (const float4*)(&hbuf[wr][0]);

  float h = 0.0f;
  hbuf[wr][g] = 0.0f;
  __builtin_amdgcn_wave_barrier();

  float x_next = Xrow[0];
  #pragma unroll 1
  for (int t = 0; t < TT; ++t) {
    const float x = x_next;
    x_next = Xrow[t < TT - 1 ? t + 1 : t];     // prefetch next step's scalar input

    vf2 ar = { __builtin_fmaf(x, wir, brs), 0.0f };
    vf2 az = { __builtin_fmaf(x, wiz, bzs), 0.0f };
    vf2 an = { bhn, 0.0f };
    const float xn = __builtin_fmaf(x, win, bin);

    #pragma unroll
    for (int q = 0; q < 8; ++q) {
      float4 h4 = hv4[q];                      // broadcast ds_read_b128
      vf2 hlo = { h4.x, h4.y };
      vf2 hhi = { h4.z, h4.w };
      ar = __builtin_elementwise_fma(hlo, w_r[2*q],     ar);
      az = __builtin_elementwise_fma(hlo, w_z[2*q],     az);
      an = __builtin_elementwise_fma(hlo, w_n[2*q],     an);
      ar = __builtin_elementwise_fma(hhi, w_r[2*q + 1], ar);
      az = __builtin_elementwise_fma(hhi, w_z[2*q + 1], az);
      an = __builtin_elementwise_fma(hhi, w_n[2*q + 1], an);
    }
    const float r = sigm(ar.x + ar.y);
    const float z = sigm(az.x + az.y);
    const float n = tanh_(__builtin_fmaf(r, an.x + an.y, xn));
    h = __builtin_fmaf(z, h - n, n);           // (1-z)*n + z*h

    hbuf[wr][g] = h;
    __builtin_amdgcn_wave_barrier();           // wave-synchronous LDS: pin ordering
  }

  // --- backward direction: exactly ONE GRU step from h0=0 on x[T-1] ---
  const float xl  = Xrow[TT - 1];
  const float rb  = sigm(__builtin_fmaf(xl, Wih_b[g],        bih_b[g]        + bhh_b[g]));
  const float zb  = sigm(__builtin_fmaf(xl, Wih_b[HH + g],   bih_b[HH + g]   + bhh_b[HH + g]));
  const float xnb =       __builtin_fmaf(xl, Wih_b[2*HH + g], bih_b[2*HH + g]);
  const float nb  = tanh_(__builtin_fmaf(rb, bhh_b[2*HH + g], xnb));
  const float hb  = nb - zb * nb;              // (1-zb)*nb + zb*0

  // --- MLP head: sigmoid(W2 @ relu(W1 @ [h_f, h_b] + b1) + b2) ---
  hbuf[wr][g]      = h;                        // h_f
  hbuf[wr][32 + g] = hb;                       // h_b
  __builtin_amdgcn_wave_barrier();

  const int j = g & 15;                        // lanes 16..31 duplicate, harmless
  const float4* W1r = (const float4*)(W1 + j * 64);
  const float4* hc4 = (const float4*)(&hbuf[wr][0]);
  float acc = b1[j];
  #pragma unroll
  for (int q = 0; q < 16; ++q) {
    float4 w  = W1r[q];
    float4 hq = hc4[q];
    acc += w.x * hq.x + w.y * hq.y + w.z * hq.z + w.w * hq.w;
  }
  float h1 = fmaxf(acc, 0.0f) * W2[j];
  h1 += __shfl_down(h1, 8, 16);
  h1 += __shfl_down(h1, 4, 16);
  h1 += __shfl_down(h1, 2, 16);
  h1 += __shfl_down(h1, 1, 16);
  if (g == 0) out[b] = sigm(h1 + b2[0]);
}

extern "C" void kernel_launch(void* const* d_in, const int* in_sizes, int n_in,
                              void* d_out, int out_size, void* d_ws, size_t ws_size,
                              hipStream_t stream) {
  const float* X     = (const float*)d_in[0];
  const float* Wih_f = (const float*)d_in[1];
  const float* Whh_f = (const float*)d_in[2];
  const float* bih_f = (const float*)d_in[3];
  const float* bhh_f = (const float*)d_in[4];
  const float* Wih_b = (const float*)d_in[5];
  // d_in[6] = W_hh_b: unused — backward direction runs exactly one step from h0=0.
  const float* bih_b = (const float*)d_in[7];
  const float* bhh_b = (const float*)d_in[8];
  const float* W1    = (const float*)d_in[9];
  const float* b1    = (const float*)d_in[10];
  const float* W2    = (const float*)d_in[11];
  const float* b2    = (const float*)d_in[12];
  float* out = (float*)d_out;

  // 2048 rows / 8 rows per block = 256 blocks of 256 threads (1 per CU).
  gru_bidir_head<<<256, 256, 0, stream>>>(X, Wih_f, Whh_f, bih_f, bhh_f,
                                          Wih_b, bih_b, bhh_b, W1, b1, W2, b2, out);
}